// Round 9
// baseline (488.795 us; speedup 1.0000x reference)
//
#include <hip/hip_runtime.h>
#include <hip/hip_fp16.h>
#include <math.h>

constexpr int N_NODES = 20000;
constexpr int DIM = 512;       // NODE_DIM == HIDDEN
constexpr int NG = 64;
constexpr int CAP = 64;        // padded adjacency capacity (avg deg 16, max ~40)
constexpr int KCH = 160;       // U-GEMM chunk: 125 x 160 = 20000 exact
constexpr int NCHUNK = (N_NODES + KCH - 1) / KCH;  // 125
constexpr int NSPLIT = 4;      // column split of U-GEMM -> 500 blocks
constexpr int RSPLIT = 5;
constexpr int CPS = (NCHUNK + RSPLIT - 1) / RSPLIT; // 25
constexpr int CGS = 32;        // cgpad stride (floats) -> 128B
constexpr int CSTR = 16;       // cursor stride (ints) -> 64B: one node per line
constexpr int NODE_BLOCKS = (N_NODES + 3) / 4;      // 5000
constexpr int INIT_BLOCKS = (N_NODES + 255) / 256;  // 79
constexpr int GEMM_TILES = 17 * 4;                  // 68 tiles for 513x256 output
constexpr int KSPLIT_TILES = GEMM_TILES * 2;        // 136: split-K by 2 (K=256 each)
constexpr int PQ_ELEMS = 513 * 256;                 // one partial buffer
constexpr int EPT = 4;                              // edges per thread
constexpr int EDGE_BLOCKS = (320000 + 256 * EPT - 1) / (256 * EPT);  // 313

// ---------------- misc ----------------
__device__ __forceinline__ int lower_bound_i(const int* __restrict__ a, int n, int v) {
  int lo = 0, hi = n;
  while (lo < hi) {
    int mid = (lo + hi) >> 1;
    if (a[mid] < v) lo = mid + 1; else hi = mid;
  }
  return lo;
}

// cursor[j]=0; block 0: ng[g], cgpad zero
__global__ __launch_bounds__(256) void node_init(const int* __restrict__ batch,
                                                 int* __restrict__ cursor,
                                                 float* __restrict__ ng,
                                                 float* __restrict__ cgpad, int n_nodes) {
  int node = blockIdx.x * 256 + threadIdx.x;
  if (node < n_nodes) cursor[(size_t)node * CSTR] = 0;
  if (blockIdx.x == 0 && threadIdx.x < 64) {
    int gg = threadIdx.x;
    int s0 = lower_bound_i(batch, n_nodes, gg);
    int e0 = lower_bound_i(batch, n_nodes, gg + 1);
    ng[gg] = (float)(e0 - s0);
    cgpad[gg * CGS] = 0.f;
  }
}

// ---- shared-memory GEMM tile body: C[M,N] = [A0; extraRow] @ (B [+ B2]), one 32x64 tile,
// K-range [kbeg,kend). A stride K (=512). B2 nullable (second K-partial combined on load).
__device__ void gemm_stack_tile(const float* __restrict__ A0, const float* __restrict__ extra,
                                const float* __restrict__ B, const float* __restrict__ B2,
                                float* __restrict__ C,
                                int N, int K, int R0, int tile, int kbeg, int kend,
                                float* As, float* Bs, int tid) {
  int bm = (tile >> 2) * 32;   // 0..16 -> 32-row tile
  int bn = (tile & 3) * 64;    // 0..3  -> 64-col tile
  int tx = tid & 15;
  int ty = tid >> 4;
  int ar = tid >> 3;
  int ac = (tid & 7) * 2;
  int br = tid >> 4;
  int bc = (tid & 15) * 4;
  float acc[2][4] = {};
  for (int k0 = kbeg; k0 < kend; k0 += 16) {
    int row = bm + ar;
    float2 av = make_float2(0.f, 0.f);
    if (row < R0)       av = *(const float2*)(A0 + (size_t)row * K + k0 + ac);
    else if (row == R0) av = *(const float2*)(extra + k0 + ac);
    As[(ac + 0) * 34 + ar] = av.x;
    As[(ac + 1) * 34 + ar] = av.y;
    size_t boff = (size_t)(k0 + br) * N + bn + bc;
    float4 bv = *(const float4*)(B + boff);
    if (B2) {
      float4 b2 = *(const float4*)(B2 + boff);
      bv.x += b2.x; bv.y += b2.y; bv.z += b2.z; bv.w += b2.w;
    }
    *(float4*)&Bs[br * 68 + bc] = bv;
    __syncthreads();
#pragma unroll
    for (int kk = 0; kk < 16; ++kk) {
      float2 a01 = *(const float2*)&As[kk * 34 + ty * 2];
      float4 b4  = *(const float4*)&Bs[kk * 68 + tx * 4];
      acc[0][0] = fmaf(a01.x, b4.x, acc[0][0]); acc[0][1] = fmaf(a01.x, b4.y, acc[0][1]);
      acc[0][2] = fmaf(a01.x, b4.z, acc[0][2]); acc[0][3] = fmaf(a01.x, b4.w, acc[0][3]);
      acc[1][0] = fmaf(a01.y, b4.x, acc[1][0]); acc[1][1] = fmaf(a01.y, b4.y, acc[1][1]);
      acc[1][2] = fmaf(a01.y, b4.z, acc[1][2]); acc[1][3] = fmaf(a01.y, b4.w, acc[1][3]);
    }
    __syncthreads();
  }
#pragma unroll
  for (int i = 0; i < 2; ++i) {
    int m = bm + ty * 2 + i;
    if (m > R0) continue;   // M = R0+1
    *(float4*)&C[(size_t)m * N + bn + tx * 4] =
        make_float4(acc[i][0], acc[i][1], acc[i][2], acc[i][3]);
  }
}

// ---------------- K2: Q GEMM tiles FIRST (split-K), then edge pass ----------------
__global__ __launch_bounds__(256) void fill_and_Q(const int* __restrict__ srcI,
                                                  const int* __restrict__ dstI,
                                                  const int* __restrict__ batch,
                                                  int* __restrict__ cursor,
                                                  int* __restrict__ edst,
                                                  float* __restrict__ cgpad,
                                                  const float* __restrict__ Wg2,
                                                  const float* __restrict__ bg2,
                                                  const float* __restrict__ Wc1,
                                                  float* __restrict__ Q, int n_edges) {
  __shared__ float As[16 * 34];
  __shared__ float Bs[16 * 68];
  __shared__ int hist[64];
  int b = blockIdx.x;
  int t = threadIdx.x;
  if (b < KSPLIT_TILES) {
    int ks = b & 1;
    int tile = b >> 1;
    gemm_stack_tile(Wg2, bg2, Wc1, nullptr, Q + (size_t)ks * PQ_ELEMS,
                    256, 512, 512, tile, ks * 256, ks * 256 + 256, As, Bs, t);
  } else {
    int eb = b - KSPLIT_TILES;
    if (t < 64) hist[t] = 0;
    __syncthreads();
    int base = eb * (256 * EPT) + t;
    int s[EPT], d[EPT], c[EPT];
    bool v[EPT];
#pragma unroll
    for (int u = 0; u < EPT; ++u) {
      int i = base + u * 256;
      v[u] = i < n_edges;
      s[u] = v[u] ? srcI[i] : 0;
    }
#pragma unroll
    for (int u = 0; u < EPT; ++u) {
      int i = base + u * 256;
      d[u] = v[u] ? dstI[i] : 0;
    }
#pragma unroll
    for (int u = 0; u < EPT; ++u)
      if (v[u]) c[u] = atomicAdd(&cursor[(size_t)s[u] * CSTR], 1);
#pragma unroll
    for (int u = 0; u < EPT; ++u)
      if (v[u]) edst[(size_t)s[u] * CAP + c[u]] = d[u];
#pragma unroll
    for (int u = 0; u < EPT; ++u)
      if (v[u]) atomicAdd(&hist[batch[d[u]]], 1);
    __syncthreads();
    if (t < 64 && hist[t] != 0) atomicAdd(&cgpad[t * CGS], (float)hist[t]);
  }
}

// ---------------- K2.5: build wT (fp16, exact small ints) from adjacency ----------------
// wT[k][g] = (batch[k]==g) + #{d in N(k): batch[d]==g}   (<= 41, exact in fp16)
__global__ __launch_bounds__(256) void build_wT(const int* __restrict__ batch,
                                                const int* __restrict__ deg,
                                                const int* __restrict__ edst,
                                                __half* __restrict__ wT, int n_nodes) {
  int node = blockIdx.x * 4 + (threadIdx.x >> 6);
  int g = threadIdx.x & 63;
  if (node >= n_nodes) return;
  int end = deg[(size_t)node * CSTR];
  const int* nb = edst + (size_t)node * CAP;
  float acc = (batch[node] == g) ? 1.f : 0.f;
  int i = 0;
  for (; i + 7 < end; i += 8) {
    int d0 = nb[i], d1 = nb[i + 1], d2 = nb[i + 2], d3 = nb[i + 3];
    int d4 = nb[i + 4], d5 = nb[i + 5], d6 = nb[i + 6], d7 = nb[i + 7];
    int b0 = batch[d0], b1 = batch[d1], b2 = batch[d2], b3 = batch[d3];
    int b4 = batch[d4], b5 = batch[d5], b6 = batch[d6], b7 = batch[d7];
    acc += ((float)(b0 == g) + (float)(b1 == g)) + ((float)(b2 == g) + (float)(b3 == g)) +
           ((float)(b4 == g) + (float)(b5 == g)) + ((float)(b6 == g) + (float)(b7 == g));
  }
  for (; i < end; ++i) acc += (float)(batch[nb[i]] == g);
  wT[(size_t)node * 64 + g] = __float2half_rn(acc);
}

// ---------------- K3: P GEMM tiles FIRST (split-K, B = Q0+Q1), then compute_cT ----------------
// cT[k][g] = wT[k][g] + sum_{d in N(k)} wT[d][g]   (<= 1681, exact in fp16)
__global__ __launch_bounds__(256) void cT_and_P(const __half* __restrict__ wT,
                                                const int* __restrict__ deg,
                                                const int* __restrict__ edst,
                                                __half* __restrict__ cT,
                                                const float* __restrict__ Wg1,
                                                const float* __restrict__ bg1,
                                                const float* __restrict__ Q,
                                                float* __restrict__ P, int n_nodes) {
  __shared__ float As[16 * 34];
  __shared__ float Bs[16 * 68];
  int b = blockIdx.x;
  int t = threadIdx.x;
  if (b < KSPLIT_TILES) {
    int ks = b & 1;
    int tile = b >> 1;
    gemm_stack_tile(Wg1, bg1, Q, Q + PQ_ELEMS, P + (size_t)ks * PQ_ELEMS,
                    256, 512, 512, tile, ks * 256, ks * 256 + 256, As, Bs, t);
  } else {
    int node = (b - KSPLIT_TILES) * 4 + (t >> 6);
    int g = t & 63;
    if (node >= n_nodes) return;
    float acc = __half2float(wT[(size_t)node * 64 + g]);
    int end = deg[(size_t)node * CSTR];
    const int* nb = edst + (size_t)node * CAP;
    int i = 0;
    for (; i + 7 < end; i += 8) {
      int d0 = nb[i], d1 = nb[i + 1], d2 = nb[i + 2], d3 = nb[i + 3];
      int d4 = nb[i + 4], d5 = nb[i + 5], d6 = nb[i + 6], d7 = nb[i + 7];
      float v0 = __half2float(wT[(size_t)d0 * 64 + g]);
      float v1 = __half2float(wT[(size_t)d1 * 64 + g]);
      float v2 = __half2float(wT[(size_t)d2 * 64 + g]);
      float v3 = __half2float(wT[(size_t)d3 * 64 + g]);
      float v4 = __half2float(wT[(size_t)d4 * 64 + g]);
      float v5 = __half2float(wT[(size_t)d5 * 64 + g]);
      float v6 = __half2float(wT[(size_t)d6 * 64 + g]);
      float v7 = __half2float(wT[(size_t)d7 * 64 + g]);
      acc += ((v0 + v1) + (v2 + v3)) + ((v4 + v5) + (v6 + v7));
    }
    for (; i + 3 < end; i += 4) {
      int d0 = nb[i], d1 = nb[i + 1], d2 = nb[i + 2], d3 = nb[i + 3];
      acc += __half2float(wT[(size_t)d0 * 64 + g]) + __half2float(wT[(size_t)d1 * 64 + g]) +
             __half2float(wT[(size_t)d2 * 64 + g]) + __half2float(wT[(size_t)d3 * 64 + g]);
    }
    for (; i < end; ++i) acc += __half2float(wT[(size_t)nb[i] * 64 + g]);
    cT[(size_t)node * 64 + g] = __float2half_rn(acc);
  }
}

// ---------------- K4: U-GEMM (fp16 LDS tile, 4 blocks/CU, dbuf x stream) ----------------
#define LOADX(X, KB)                                                      \
  _Pragma("unroll")                                                       \
  for (int t_ = 0; t_ < 4; ++t_) {                                        \
    X[t_] = x2[(size_t)(k0 + (KB) + t_) * 256 + ncol];                    \
  }

#define COMPX(X, KB)                                                      \
  _Pragma("unroll")                                                       \
  for (int t_ = 0; t_ < 4; ++t_) {                                        \
    const __half2* hp_ = (const __half2*)&scT[(KB) + t_][w * 8];          \
    float2 c0_ = __half22float2(hp_[0]);                                  \
    float2 c1_ = __half22float2(hp_[1]);                                  \
    float2 c2_ = __half22float2(hp_[2]);                                  \
    float2 c3_ = __half22float2(hp_[3]);                                  \
    float cv_[8] = {c0_.x, c0_.y, c1_.x, c1_.y, c2_.x, c2_.y, c3_.x, c3_.y}; \
    _Pragma("unroll")                                                     \
    for (int q_ = 0; q_ < 8; ++q_) {                                      \
      acc[q_].x = fmaf(cv_[q_], X[t_].x, acc[q_].x);                      \
      acc[q_].y = fmaf(cv_[q_], X[t_].y, acc[q_].y);                      \
    }                                                                     \
  }

__global__ __launch_bounds__(512, 8) void ugemm(const float* __restrict__ x,
                                                const __half* __restrict__ cT,
                                                float* __restrict__ Upart, int n_nodes) {
  __shared__ __half scT[KCH][64];  // 20 KB fp16
  int c = blockIdx.y;
  int nx = blockIdx.x;            // column quarter
  int t = threadIdx.x;
  int w = t >> 6;                 // wave 0..7
  int g = t & 63;                 // lane
  int k0 = c * KCH;
  int kmax = (n_nodes - k0) < KCH ? (n_nodes - k0) : KCH;  // 160 (125*160==20000)
  {
    // coalesced fp16 copy (4 halves per thread per iter)
    const uint2* src = (const uint2*)(cT + (size_t)k0 * 64);
    uint2* dst = (uint2*)(&scT[0][0]);
    int limit = kmax * 16;        // kmax*64 halves / 4
    for (int i = t; i < limit; i += 512) dst[i] = src[i];
  }
  __syncthreads();
  const float2* x2 = (const float2*)x;
  int ncol = nx * 64 + g;         // one float2 column per lane
  float2 acc[8];
#pragma unroll
  for (int q = 0; q < 8; ++q) acc[q] = make_float2(0.f, 0.f);
  float2 xa[4], xb[4];
  LOADX(xa, 0);
  for (int kk = 0; kk < kmax; kk += 8) {
    LOADX(xb, kk + 4);
    COMPX(xa, kk);
    if (kk + 8 < kmax) { LOADX(xa, kk + 8); }
    COMPX(xb, kk + 4);
  }
  float2* up = (float2*)Upart;
#pragma unroll
  for (int q = 0; q < 8; ++q) {
    int gg = w * 8 + q;
    up[((size_t)c * 64 + gg) * 256 + ncol] = acc[q];
  }
}

// ---------------- Upart reduce: Ured[s][g][n] = sum_{c in split s} Upart[c][g][n] ----------------
__global__ __launch_bounds__(128) void reduce_U(const float* __restrict__ Upart,
                                                float* __restrict__ Ured) {
  int g = blockIdx.x;   // 0..63
  int s = blockIdx.y;   // 0..RSPLIT-1
  int t = threadIdx.x;  // 0..127 float4 over 512
  int c0 = s * CPS;
  int c1 = (c0 + CPS < NCHUNK) ? c0 + CPS : NCHUNK;
  const float4* up = (const float4*)Upart;
  float4 acc = make_float4(0.f, 0.f, 0.f, 0.f);
  for (int c = c0; c < c1; ++c) {
    float4 v = up[((size_t)c * 64 + g) * 128 + t];
    acc.x += v.x; acc.y += v.y; acc.z += v.z; acc.w += v.w;
  }
  ((float4*)Ured)[((size_t)s * 64 + g) * 128 + t] = acc;
}

// ---------------- fused head ----------------
// P = two K-partials of [Wc; v1]; Q = two K-partials of [*; v2]; cg = ng + edge-hist
__global__ __launch_bounds__(256) void head(const float* __restrict__ Ured,
                                            const float* __restrict__ P,
                                            const float* __restrict__ Q,
                                            const float* __restrict__ ng,
                                            const float* __restrict__ cgpad,
                                            const float* __restrict__ bc1,
                                            const float* __restrict__ Wc2,
                                            const float* __restrict__ bc2,
                                            float* __restrict__ out) {
  int g = blockIdx.x;
  int j = threadIdx.x;
  const float* Wc0 = P;
  const float* Wc1p = P + (size_t)PQ_ELEMS;
  const float* v1a = P + (size_t)512 * 256;
  const float* v1b = P + (size_t)PQ_ELEMS + (size_t)512 * 256;
  const float* v2a = Q + (size_t)512 * 256;
  const float* v2b = Q + (size_t)PQ_ELEMS + (size_t)512 * 256;
  __shared__ float p[512];
  float s0 = 0.f, s1 = 0.f;
#pragma unroll
  for (int s = 0; s < RSPLIT; ++s) {
    s0 += Ured[((size_t)s * 64 + g) * DIM + j];
    s1 += Ured[((size_t)s * 64 + g) * DIM + 256 + j];
  }
  p[j] = s0;
  p[j + 256] = s1;
  __syncthreads();
  float cg = ng[g] + cgpad[g * CGS];
  float acc = bc1[j] + cg * (v1a[j] + v1b[j]) + ng[g] * (v2a[j] + v2b[j]);
  for (int k = 0; k < 512; ++k) {
    float w = Wc0[k * 256 + j] + Wc1p[k * 256 + j];
    acc = fmaf(p[k], w, acc);
  }
  float z = fmaxf(acc, 0.f);
  float part = z * Wc2[j];
  for (int off = 32; off > 0; off >>= 1) part += __shfl_down(part, off, 64);
  __shared__ float red[4];
  if ((j & 63) == 0) red[j >> 6] = part;
  __syncthreads();
  if (j == 0) {
    float tot = red[0] + red[1] + red[2] + red[3] + bc2[0];
    out[g] = 1.f / (1.f + expf(-tot));
  }
}

extern "C" void kernel_launch(void* const* d_in, const int* in_sizes, int n_in,
                              void* d_out, int out_size, void* d_ws, size_t ws_size,
                              hipStream_t stream) {
  const float* x    = (const float*)d_in[0];
  const int*   ei   = (const int*)d_in[1];
  const int*   batch= (const int*)d_in[2];
  const float* Wg1  = (const float*)d_in[3];
  const float* bg1  = (const float*)d_in[4];
  const float* Wg2  = (const float*)d_in[5];
  const float* bg2  = (const float*)d_in[6];
  const float* Wc1  = (const float*)d_in[7];
  const float* bc1  = (const float*)d_in[8];
  const float* Wc2  = (const float*)d_in[9];
  const float* bc2  = (const float*)d_in[10];
  float* out = (float*)d_out;

  int n_edges = in_sizes[1] / 2;
  int n_nodes = in_sizes[2];
  const int* srcI = ei;
  const int* dstI = ei + n_edges;

  char* ws = (char*)d_ws;
  size_t off = 0;
  auto alloc = [&](size_t bytes) { char* p = ws + off; off += (bytes + 255) & ~(size_t)255; return p; };
  __half* wT   = (__half*)alloc((size_t)N_NODES * 64 * sizeof(__half));      // 2.56 MB
  __half* cT   = (__half*)alloc((size_t)N_NODES * 64 * sizeof(__half));      // 2.56 MB
  float* Upart = (float*)alloc((size_t)NCHUNK * 64 * DIM * sizeof(float));   // 16.4 MB
  float* Ured  = (float*)alloc((size_t)RSPLIT * 64 * DIM * sizeof(float));   // 655 KB
  float* Q     = (float*)alloc((size_t)2 * PQ_ELEMS * sizeof(float));        // split-K partials
  float* P     = (float*)alloc((size_t)2 * PQ_ELEMS * sizeof(float));        // split-K partials
  float* ng    = (float*)alloc(NG * sizeof(float));
  float* cgpad = (float*)alloc(NG * CGS * sizeof(float));
  int* cursor  = (int*)alloc((size_t)N_NODES * CSTR * sizeof(int));          // 1.28 MB padded
  int* edst    = (int*)alloc((size_t)N_NODES * CAP * sizeof(int));           // 5.12 MB padded adj

  // K1: cursor zero + ng/cgpad init
  node_init<<<INIT_BLOCKS, 256, 0, stream>>>(batch, cursor, ng, cgpad, n_nodes);
  // K2: Q GEMM tiles (split-K, first) || edge pass (adjacency fill + cg hist)
  fill_and_Q<<<KSPLIT_TILES + EDGE_BLOCKS, 256, 0, stream>>>(srcI, dstI, batch, cursor, edst,
                                                             cgpad, Wg2, bg2, Wc1, Q, n_edges);
  // K2.5: wT (fp16) from adjacency (pure gather, 5000 blocks)
  build_wT<<<NODE_BLOCKS, 256, 0, stream>>>(batch, cursor, edst, wT, n_nodes);
  // K3: P GEMM tiles (split-K, B=Q0+Q1, first) || cT gather (fp16 rows, 5000 blocks)
  cT_and_P<<<KSPLIT_TILES + NODE_BLOCKS, 256, 0, stream>>>(wT, cursor, edst, cT,
                                                           Wg1, bg1, Q, P, n_nodes);
  // K4: U partials (fp16 LDS tile, 4 blocks/CU, double-buffered x stream)
  ugemm<<<dim3(NSPLIT, NCHUNK), 512, 0, stream>>>(x, cT, Upart, n_nodes);
  // K5: reduce partials
  reduce_U<<<dim3(64, RSPLIT), 128, 0, stream>>>(Upart, Ured);
  // K6: head
  head<<<NG, 256, 0, stream>>>(Ured, P, Q, ng, cgpad, bc1, Wc2, bc2, out);
}

// Round 10
// 211.981 us; speedup vs baseline: 2.3058x; 2.3058x over previous
//
#include <hip/hip_runtime.h>
#include <hip/hip_fp16.h>
#include <math.h>

constexpr int N_NODES = 20000;
constexpr int DIM = 512;       // NODE_DIM == HIDDEN
constexpr int NG = 64;
constexpr int CAP = 64;        // padded adjacency capacity (avg deg 16, max ~40)
constexpr int KCH = 160;       // U-GEMM chunk: 125 x 160 = 20000 exact
constexpr int NCHUNK = (N_NODES + KCH - 1) / KCH;  // 125
constexpr int NSPLIT = 4;      // column split of U-GEMM -> 500 blocks
constexpr int RSPLIT = 5;
constexpr int CPS = (NCHUNK + RSPLIT - 1) / RSPLIT; // 25
constexpr int CGS = 32;        // cgpad stride (floats) -> 128B
constexpr int CSTR = 16;       // cursor stride (ints) -> 64B: one node per line
constexpr int NODE_BLOCKS = (N_NODES + 3) / 4;      // 5000
constexpr int INIT_BLOCKS = (N_NODES + 255) / 256;  // 79
constexpr int GEMM_TILES = 17 * 4;                  // 68 tiles for 513x256 output
constexpr int KSPLIT_TILES = GEMM_TILES * 2;        // 136: split-K by 2 (K=256 each)
constexpr int PQ_ELEMS = 513 * 256;                 // one partial buffer
constexpr int EPT = 4;                              // edges per thread
constexpr int EDGE_BLOCKS = (320000 + 256 * EPT - 1) / (256 * EPT);  // 313

// ---------------- misc ----------------
__device__ __forceinline__ int lower_bound_i(const int* __restrict__ a, int n, int v) {
  int lo = 0, hi = n;
  while (lo < hi) {
    int mid = (lo + hi) >> 1;
    if (a[mid] < v) lo = mid + 1; else hi = mid;
  }
  return lo;
}

// cursor[j]=0; block 0: ng[g], cgpad zero
__global__ __launch_bounds__(256) void node_init(const int* __restrict__ batch,
                                                 int* __restrict__ cursor,
                                                 float* __restrict__ ng,
                                                 float* __restrict__ cgpad, int n_nodes) {
  int node = blockIdx.x * 256 + threadIdx.x;
  if (node < n_nodes) cursor[(size_t)node * CSTR] = 0;
  if (blockIdx.x == 0 && threadIdx.x < 64) {
    int gg = threadIdx.x;
    int s0 = lower_bound_i(batch, n_nodes, gg);
    int e0 = lower_bound_i(batch, n_nodes, gg + 1);
    ng[gg] = (float)(e0 - s0);
    cgpad[gg * CGS] = 0.f;
  }
}

// ---- shared-memory GEMM tile body: C[M,N] = [A0; extraRow] @ (B [+ B2]), one 32x64 tile,
// K-range [kbeg,kend). A stride K (=512). B2 nullable (second K-partial combined on load).
__device__ void gemm_stack_tile(const float* __restrict__ A0, const float* __restrict__ extra,
                                const float* __restrict__ B, const float* __restrict__ B2,
                                float* __restrict__ C,
                                int N, int K, int R0, int tile, int kbeg, int kend,
                                float* As, float* Bs, int tid) {
  int bm = (tile >> 2) * 32;   // 0..16 -> 32-row tile
  int bn = (tile & 3) * 64;    // 0..3  -> 64-col tile
  int tx = tid & 15;
  int ty = tid >> 4;
  int ar = tid >> 3;
  int ac = (tid & 7) * 2;
  int br = tid >> 4;
  int bc = (tid & 15) * 4;
  float acc[2][4] = {};
  for (int k0 = kbeg; k0 < kend; k0 += 16) {
    int row = bm + ar;
    float2 av = make_float2(0.f, 0.f);
    if (row < R0)       av = *(const float2*)(A0 + (size_t)row * K + k0 + ac);
    else if (row == R0) av = *(const float2*)(extra + k0 + ac);
    As[(ac + 0) * 34 + ar] = av.x;
    As[(ac + 1) * 34 + ar] = av.y;
    size_t boff = (size_t)(k0 + br) * N + bn + bc;
    float4 bv = *(const float4*)(B + boff);
    if (B2) {
      float4 b2 = *(const float4*)(B2 + boff);
      bv.x += b2.x; bv.y += b2.y; bv.z += b2.z; bv.w += b2.w;
    }
    *(float4*)&Bs[br * 68 + bc] = bv;
    __syncthreads();
#pragma unroll
    for (int kk = 0; kk < 16; ++kk) {
      float2 a01 = *(const float2*)&As[kk * 34 + ty * 2];
      float4 b4  = *(const float4*)&Bs[kk * 68 + tx * 4];
      acc[0][0] = fmaf(a01.x, b4.x, acc[0][0]); acc[0][1] = fmaf(a01.x, b4.y, acc[0][1]);
      acc[0][2] = fmaf(a01.x, b4.z, acc[0][2]); acc[0][3] = fmaf(a01.x, b4.w, acc[0][3]);
      acc[1][0] = fmaf(a01.y, b4.x, acc[1][0]); acc[1][1] = fmaf(a01.y, b4.y, acc[1][1]);
      acc[1][2] = fmaf(a01.y, b4.z, acc[1][2]); acc[1][3] = fmaf(a01.y, b4.w, acc[1][3]);
    }
    __syncthreads();
  }
#pragma unroll
  for (int i = 0; i < 2; ++i) {
    int m = bm + ty * 2 + i;
    if (m > R0) continue;   // M = R0+1
    *(float4*)&C[(size_t)m * N + bn + tx * 4] =
        make_float4(acc[i][0], acc[i][1], acc[i][2], acc[i][3]);
  }
}

// ---------------- K2: Q GEMM tiles FIRST (split-K), then edge pass ----------------
__global__ __launch_bounds__(256) void fill_and_Q(const int* __restrict__ srcI,
                                                  const int* __restrict__ dstI,
                                                  const int* __restrict__ batch,
                                                  int* __restrict__ cursor,
                                                  int* __restrict__ edst,
                                                  float* __restrict__ cgpad,
                                                  const float* __restrict__ Wg2,
                                                  const float* __restrict__ bg2,
                                                  const float* __restrict__ Wc1,
                                                  float* __restrict__ Q, int n_edges) {
  __shared__ float As[16 * 34];
  __shared__ float Bs[16 * 68];
  __shared__ int hist[64];
  int b = blockIdx.x;
  int t = threadIdx.x;
  if (b < KSPLIT_TILES) {
    int ks = b & 1;
    int tile = b >> 1;
    gemm_stack_tile(Wg2, bg2, Wc1, nullptr, Q + (size_t)ks * PQ_ELEMS,
                    256, 512, 512, tile, ks * 256, ks * 256 + 256, As, Bs, t);
  } else {
    int eb = b - KSPLIT_TILES;
    if (t < 64) hist[t] = 0;
    __syncthreads();
    int base = eb * (256 * EPT) + t;
    int s[EPT], d[EPT], c[EPT];
    bool v[EPT];
#pragma unroll
    for (int u = 0; u < EPT; ++u) {
      int i = base + u * 256;
      v[u] = i < n_edges;
      s[u] = v[u] ? srcI[i] : 0;
    }
#pragma unroll
    for (int u = 0; u < EPT; ++u) {
      int i = base + u * 256;
      d[u] = v[u] ? dstI[i] : 0;
    }
#pragma unroll
    for (int u = 0; u < EPT; ++u)
      if (v[u]) c[u] = atomicAdd(&cursor[(size_t)s[u] * CSTR], 1);
#pragma unroll
    for (int u = 0; u < EPT; ++u)
      if (v[u]) edst[(size_t)s[u] * CAP + c[u]] = d[u];
#pragma unroll
    for (int u = 0; u < EPT; ++u)
      if (v[u]) atomicAdd(&hist[batch[d[u]]], 1);
    __syncthreads();
    if (t < 64 && hist[t] != 0) atomicAdd(&cgpad[t * CGS], (float)hist[t]);
  }
}

// ---------------- K2.5: build wT (fp16, exact small ints) from adjacency ----------------
// wT[k][g] = (batch[k]==g) + #{d in N(k): batch[d]==g}   (<= 41, exact in fp16)
__global__ __launch_bounds__(256) void build_wT(const int* __restrict__ batch,
                                                const int* __restrict__ deg,
                                                const int* __restrict__ edst,
                                                __half* __restrict__ wT, int n_nodes) {
  int node = blockIdx.x * 4 + (threadIdx.x >> 6);
  int g = threadIdx.x & 63;
  if (node >= n_nodes) return;
  int end = deg[(size_t)node * CSTR];
  const int* nb = edst + (size_t)node * CAP;
  float acc = (batch[node] == g) ? 1.f : 0.f;
  int i = 0;
  for (; i + 7 < end; i += 8) {
    int d0 = nb[i], d1 = nb[i + 1], d2 = nb[i + 2], d3 = nb[i + 3];
    int d4 = nb[i + 4], d5 = nb[i + 5], d6 = nb[i + 6], d7 = nb[i + 7];
    int b0 = batch[d0], b1 = batch[d1], b2 = batch[d2], b3 = batch[d3];
    int b4 = batch[d4], b5 = batch[d5], b6 = batch[d6], b7 = batch[d7];
    acc += ((float)(b0 == g) + (float)(b1 == g)) + ((float)(b2 == g) + (float)(b3 == g)) +
           ((float)(b4 == g) + (float)(b5 == g)) + ((float)(b6 == g) + (float)(b7 == g));
  }
  for (; i < end; ++i) acc += (float)(batch[nb[i]] == g);
  wT[(size_t)node * 64 + g] = __float2half_rn(acc);
}

// ---------------- K3: P GEMM tiles FIRST (split-K, B = Q0+Q1), then compute_cT ----------------
// cT[k][g] = wT[k][g] + sum_{d in N(k)} wT[d][g]   (<= 1681, exact in fp16)
__global__ __launch_bounds__(256) void cT_and_P(const __half* __restrict__ wT,
                                                const int* __restrict__ deg,
                                                const int* __restrict__ edst,
                                                __half* __restrict__ cT,
                                                const float* __restrict__ Wg1,
                                                const float* __restrict__ bg1,
                                                const float* __restrict__ Q,
                                                float* __restrict__ P, int n_nodes) {
  __shared__ float As[16 * 34];
  __shared__ float Bs[16 * 68];
  int b = blockIdx.x;
  int t = threadIdx.x;
  if (b < KSPLIT_TILES) {
    int ks = b & 1;
    int tile = b >> 1;
    gemm_stack_tile(Wg1, bg1, Q, Q + PQ_ELEMS, P + (size_t)ks * PQ_ELEMS,
                    256, 512, 512, tile, ks * 256, ks * 256 + 256, As, Bs, t);
  } else {
    int node = (b - KSPLIT_TILES) * 4 + (t >> 6);
    int g = t & 63;
    if (node >= n_nodes) return;
    float acc = __half2float(wT[(size_t)node * 64 + g]);
    int end = deg[(size_t)node * CSTR];
    const int* nb = edst + (size_t)node * CAP;
    int i = 0;
    for (; i + 7 < end; i += 8) {
      int d0 = nb[i], d1 = nb[i + 1], d2 = nb[i + 2], d3 = nb[i + 3];
      int d4 = nb[i + 4], d5 = nb[i + 5], d6 = nb[i + 6], d7 = nb[i + 7];
      float v0 = __half2float(wT[(size_t)d0 * 64 + g]);
      float v1 = __half2float(wT[(size_t)d1 * 64 + g]);
      float v2 = __half2float(wT[(size_t)d2 * 64 + g]);
      float v3 = __half2float(wT[(size_t)d3 * 64 + g]);
      float v4 = __half2float(wT[(size_t)d4 * 64 + g]);
      float v5 = __half2float(wT[(size_t)d5 * 64 + g]);
      float v6 = __half2float(wT[(size_t)d6 * 64 + g]);
      float v7 = __half2float(wT[(size_t)d7 * 64 + g]);
      acc += ((v0 + v1) + (v2 + v3)) + ((v4 + v5) + (v6 + v7));
    }
    for (; i + 3 < end; i += 4) {
      int d0 = nb[i], d1 = nb[i + 1], d2 = nb[i + 2], d3 = nb[i + 3];
      acc += __half2float(wT[(size_t)d0 * 64 + g]) + __half2float(wT[(size_t)d1 * 64 + g]) +
             __half2float(wT[(size_t)d2 * 64 + g]) + __half2float(wT[(size_t)d3 * 64 + g]);
    }
    for (; i < end; ++i) acc += __half2float(wT[(size_t)nb[i] * 64 + g]);
    cT[(size_t)node * 64 + g] = __float2half_rn(acc);
  }
}

// ---------------- K4: U-GEMM (fp16 LDS tile, natural VGPR, dbuf x stream) ----------------
#define LOADX(X, KB)                                                      \
  _Pragma("unroll")                                                       \
  for (int t_ = 0; t_ < 4; ++t_) {                                        \
    X[t_] = x2[(size_t)(k0 + (KB) + t_) * 256 + ncol];                    \
  }

#define COMPX(X, KB)                                                      \
  _Pragma("unroll")                                                       \
  for (int t_ = 0; t_ < 4; ++t_) {                                        \
    const __half2* hp_ = (const __half2*)&scT[(KB) + t_][w * 8];          \
    float2 c0_ = __half22float2(hp_[0]);                                  \
    float2 c1_ = __half22float2(hp_[1]);                                  \
    float2 c2_ = __half22float2(hp_[2]);                                  \
    float2 c3_ = __half22float2(hp_[3]);                                  \
    float cv_[8] = {c0_.x, c0_.y, c1_.x, c1_.y, c2_.x, c2_.y, c3_.x, c3_.y}; \
    _Pragma("unroll")                                                     \
    for (int q_ = 0; q_ < 8; ++q_) {                                      \
      acc[q_].x = fmaf(cv_[q_], X[t_].x, acc[q_].x);                      \
      acc[q_].y = fmaf(cv_[q_], X[t_].y, acc[q_].y);                      \
    }                                                                     \
  }

__global__ __launch_bounds__(512) void ugemm(const float* __restrict__ x,
                                             const __half* __restrict__ cT,
                                             float* __restrict__ Upart, int n_nodes) {
  __shared__ __half scT[KCH][64];  // 20 KB fp16
  int c = blockIdx.y;
  int nx = blockIdx.x;            // column quarter
  int t = threadIdx.x;
  int w = t >> 6;                 // wave 0..7
  int g = t & 63;                 // lane
  int k0 = c * KCH;
  int kmax = (n_nodes - k0) < KCH ? (n_nodes - k0) : KCH;  // 160 (125*160==20000)
  {
    // coalesced fp16 copy (4 halves per thread per iter)
    const uint2* src = (const uint2*)(cT + (size_t)k0 * 64);
    uint2* dst = (uint2*)(&scT[0][0]);
    int limit = kmax * 16;        // kmax*64 halves / 4
    for (int i = t; i < limit; i += 512) dst[i] = src[i];
  }
  __syncthreads();
  const float2* x2 = (const float2*)x;
  int ncol = nx * 64 + g;         // one float2 column per lane
  float2 acc[8];
#pragma unroll
  for (int q = 0; q < 8; ++q) acc[q] = make_float2(0.f, 0.f);
  float2 xa[4], xb[4];
  LOADX(xa, 0);
  for (int kk = 0; kk < kmax; kk += 8) {
    LOADX(xb, kk + 4);
    COMPX(xa, kk);
    if (kk + 8 < kmax) { LOADX(xa, kk + 8); }
    COMPX(xb, kk + 4);
  }
  float2* up = (float2*)Upart;
#pragma unroll
  for (int q = 0; q < 8; ++q) {
    int gg = w * 8 + q;
    up[((size_t)c * 64 + gg) * 256 + ncol] = acc[q];
  }
}

// ---------------- Upart reduce: Ured[s][g][n] = sum_{c in split s} Upart[c][g][n] ----------------
__global__ __launch_bounds__(128) void reduce_U(const float* __restrict__ Upart,
                                                float* __restrict__ Ured) {
  int g = blockIdx.x;   // 0..63
  int s = blockIdx.y;   // 0..RSPLIT-1
  int t = threadIdx.x;  // 0..127 float4 over 512
  int c0 = s * CPS;
  int c1 = (c0 + CPS < NCHUNK) ? c0 + CPS : NCHUNK;
  const float4* up = (const float4*)Upart;
  float4 acc = make_float4(0.f, 0.f, 0.f, 0.f);
  for (int c = c0; c < c1; ++c) {
    float4 v = up[((size_t)c * 64 + g) * 128 + t];
    acc.x += v.x; acc.y += v.y; acc.z += v.z; acc.w += v.w;
  }
  ((float4*)Ured)[((size_t)s * 64 + g) * 128 + t] = acc;
}

// ---------------- fused head ----------------
// P = two K-partials of [Wc; v1]; Q = two K-partials of [*; v2]; cg = ng + edge-hist
__global__ __launch_bounds__(256) void head(const float* __restrict__ Ured,
                                            const float* __restrict__ P,
                                            const float* __restrict__ Q,
                                            const float* __restrict__ ng,
                                            const float* __restrict__ cgpad,
                                            const float* __restrict__ bc1,
                                            const float* __restrict__ Wc2,
                                            const float* __restrict__ bc2,
                                            float* __restrict__ out) {
  int g = blockIdx.x;
  int j = threadIdx.x;
  const float* Wc0 = P;
  const float* Wc1p = P + (size_t)PQ_ELEMS;
  const float* v1a = P + (size_t)512 * 256;
  const float* v1b = P + (size_t)PQ_ELEMS + (size_t)512 * 256;
  const float* v2a = Q + (size_t)512 * 256;
  const float* v2b = Q + (size_t)PQ_ELEMS + (size_t)512 * 256;
  __shared__ float p[512];
  float s0 = 0.f, s1 = 0.f;
#pragma unroll
  for (int s = 0; s < RSPLIT; ++s) {
    s0 += Ured[((size_t)s * 64 + g) * DIM + j];
    s1 += Ured[((size_t)s * 64 + g) * DIM + 256 + j];
  }
  p[j] = s0;
  p[j + 256] = s1;
  __syncthreads();
  float cg = ng[g] + cgpad[g * CGS];
  float acc = bc1[j] + cg * (v1a[j] + v1b[j]) + ng[g] * (v2a[j] + v2b[j]);
  for (int k = 0; k < 512; ++k) {
    float w = Wc0[k * 256 + j] + Wc1p[k * 256 + j];
    acc = fmaf(p[k], w, acc);
  }
  float z = fmaxf(acc, 0.f);
  float part = z * Wc2[j];
  for (int off = 32; off > 0; off >>= 1) part += __shfl_down(part, off, 64);
  __shared__ float red[4];
  if ((j & 63) == 0) red[j >> 6] = part;
  __syncthreads();
  if (j == 0) {
    float tot = red[0] + red[1] + red[2] + red[3] + bc2[0];
    out[g] = 1.f / (1.f + expf(-tot));
  }
}

extern "C" void kernel_launch(void* const* d_in, const int* in_sizes, int n_in,
                              void* d_out, int out_size, void* d_ws, size_t ws_size,
                              hipStream_t stream) {
  const float* x    = (const float*)d_in[0];
  const int*   ei   = (const int*)d_in[1];
  const int*   batch= (const int*)d_in[2];
  const float* Wg1  = (const float*)d_in[3];
  const float* bg1  = (const float*)d_in[4];
  const float* Wg2  = (const float*)d_in[5];
  const float* bg2  = (const float*)d_in[6];
  const float* Wc1  = (const float*)d_in[7];
  const float* bc1  = (const float*)d_in[8];
  const float* Wc2  = (const float*)d_in[9];
  const float* bc2  = (const float*)d_in[10];
  float* out = (float*)d_out;

  int n_edges = in_sizes[1] / 2;
  int n_nodes = in_sizes[2];
  const int* srcI = ei;
  const int* dstI = ei + n_edges;

  char* ws = (char*)d_ws;
  size_t off = 0;
  auto alloc = [&](size_t bytes) { char* p = ws + off; off += (bytes + 255) & ~(size_t)255; return p; };
  __half* wT   = (__half*)alloc((size_t)N_NODES * 64 * sizeof(__half));      // 2.56 MB
  __half* cT   = (__half*)alloc((size_t)N_NODES * 64 * sizeof(__half));      // 2.56 MB
  float* Upart = (float*)alloc((size_t)NCHUNK * 64 * DIM * sizeof(float));   // 16.4 MB
  float* Ured  = (float*)alloc((size_t)RSPLIT * 64 * DIM * sizeof(float));   // 655 KB
  float* Q     = (float*)alloc((size_t)2 * PQ_ELEMS * sizeof(float));        // split-K partials
  float* P     = (float*)alloc((size_t)2 * PQ_ELEMS * sizeof(float));        // split-K partials
  float* ng    = (float*)alloc(NG * sizeof(float));
  float* cgpad = (float*)alloc(NG * CGS * sizeof(float));
  int* cursor  = (int*)alloc((size_t)N_NODES * CSTR * sizeof(int));          // 1.28 MB padded
  int* edst    = (int*)alloc((size_t)N_NODES * CAP * sizeof(int));           // 5.12 MB padded adj

  // K1: cursor zero + ng/cgpad init
  node_init<<<INIT_BLOCKS, 256, 0, stream>>>(batch, cursor, ng, cgpad, n_nodes);
  // K2: Q GEMM tiles (split-K, first) || edge pass (adjacency fill + cg hist)
  fill_and_Q<<<KSPLIT_TILES + EDGE_BLOCKS, 256, 0, stream>>>(srcI, dstI, batch, cursor, edst,
                                                             cgpad, Wg2, bg2, Wc1, Q, n_edges);
  // K2.5: wT (fp16) from adjacency (pure gather, 5000 blocks)
  build_wT<<<NODE_BLOCKS, 256, 0, stream>>>(batch, cursor, edst, wT, n_nodes);
  // K3: P GEMM tiles (split-K, B=Q0+Q1, first) || cT gather (fp16 rows, 5000 blocks)
  cT_and_P<<<KSPLIT_TILES + NODE_BLOCKS, 256, 0, stream>>>(wT, cursor, edst, cT,
                                                           Wg1, bg1, Q, P, n_nodes);
  // K4: U partials (fp16 LDS tile, natural VGPR allocation, double-buffered x stream)
  ugemm<<<dim3(NSPLIT, NCHUNK), 512, 0, stream>>>(x, cT, Upart, n_nodes);
  // K5: reduce partials
  reduce_U<<<dim3(64, RSPLIT), 128, 0, stream>>>(Upart, Ured);
  // K6: head
  head<<<NG, 256, 0, stream>>>(Ured, P, Q, ng, cgpad, bc1, Wc2, bc2, out);
}

// Round 11
// 209.366 us; speedup vs baseline: 2.3346x; 1.0125x over previous
//
#include <hip/hip_runtime.h>
#include <hip/hip_fp16.h>
#include <math.h>

constexpr int N_NODES = 20000;
constexpr int DIM = 512;       // NODE_DIM == HIDDEN
constexpr int NG = 64;
constexpr int CAP = 64;        // padded adjacency capacity (avg deg 16, max ~40)
constexpr int KCH = 160;       // U-GEMM chunk: 125 x 160 = 20000 exact
constexpr int NCHUNK = (N_NODES + KCH - 1) / KCH;  // 125
constexpr int NSPLIT = 4;      // column split of U-GEMM -> 500 blocks
constexpr int RSPLIT = 5;
constexpr int CPS = (NCHUNK + RSPLIT - 1) / RSPLIT; // 25
constexpr int CGS = 32;        // cgpad stride (floats) -> 128B
constexpr int CSTR = 16;       // cursor stride (ints) -> 64B: one node per line
constexpr int NODE_BLOCKS = (N_NODES + 3) / 4;      // 5000
constexpr int INIT_BLOCKS = (N_NODES + 255) / 256;  // 79
constexpr int GEMM_TILES = 17 * 4;                  // 68 tiles for 513x256 output
constexpr int KSPLIT_TILES = GEMM_TILES * 2;        // 136: split-K by 2 (K=256 each)
constexpr int COLSUM_BLOCKS = 80;                   // wT column-sum blocks (appended to K3)
constexpr int PQ_ELEMS = 513 * 256;                 // one partial buffer
constexpr int EPT = 4;                              // edges per thread
constexpr int EDGE_BLOCKS = (320000 + 256 * EPT - 1) / (256 * EPT);  // 313

// ---------------- misc ----------------
__device__ __forceinline__ int lower_bound_i(const int* __restrict__ a, int n, int v) {
  int lo = 0, hi = n;
  while (lo < hi) {
    int mid = (lo + hi) >> 1;
    if (a[mid] < v) lo = mid + 1; else hi = mid;
  }
  return lo;
}

// cursor[j]=0; block 0: ng[g], cgpad zero
__global__ __launch_bounds__(256) void node_init(const int* __restrict__ batch,
                                                 int* __restrict__ cursor,
                                                 float* __restrict__ ng,
                                                 float* __restrict__ cgpad, int n_nodes) {
  int node = blockIdx.x * 256 + threadIdx.x;
  if (node < n_nodes) cursor[(size_t)node * CSTR] = 0;
  if (blockIdx.x == 0 && threadIdx.x < 64) {
    int gg = threadIdx.x;
    int s0 = lower_bound_i(batch, n_nodes, gg);
    int e0 = lower_bound_i(batch, n_nodes, gg + 1);
    ng[gg] = (float)(e0 - s0);
    cgpad[gg * CGS] = 0.f;
  }
}

// ---- shared-memory GEMM tile body: C[M,N] = [A0; extraRow] @ (B [+ B2]), one 32x64 tile,
// K-range [kbeg,kend). A stride K (=512). B2 nullable (second K-partial combined on load).
__device__ void gemm_stack_tile(const float* __restrict__ A0, const float* __restrict__ extra,
                                const float* __restrict__ B, const float* __restrict__ B2,
                                float* __restrict__ C,
                                int N, int K, int R0, int tile, int kbeg, int kend,
                                float* As, float* Bs, int tid) {
  int bm = (tile >> 2) * 32;   // 0..16 -> 32-row tile
  int bn = (tile & 3) * 64;    // 0..3  -> 64-col tile
  int tx = tid & 15;
  int ty = tid >> 4;
  int ar = tid >> 3;
  int ac = (tid & 7) * 2;
  int br = tid >> 4;
  int bc = (tid & 15) * 4;
  float acc[2][4] = {};
  for (int k0 = kbeg; k0 < kend; k0 += 16) {
    int row = bm + ar;
    float2 av = make_float2(0.f, 0.f);
    if (row < R0)       av = *(const float2*)(A0 + (size_t)row * K + k0 + ac);
    else if (row == R0) av = *(const float2*)(extra + k0 + ac);
    As[(ac + 0) * 34 + ar] = av.x;
    As[(ac + 1) * 34 + ar] = av.y;
    size_t boff = (size_t)(k0 + br) * N + bn + bc;
    float4 bv = *(const float4*)(B + boff);
    if (B2) {
      float4 b2 = *(const float4*)(B2 + boff);
      bv.x += b2.x; bv.y += b2.y; bv.z += b2.z; bv.w += b2.w;
    }
    *(float4*)&Bs[br * 68 + bc] = bv;
    __syncthreads();
#pragma unroll
    for (int kk = 0; kk < 16; ++kk) {
      float2 a01 = *(const float2*)&As[kk * 34 + ty * 2];
      float4 b4  = *(const float4*)&Bs[kk * 68 + tx * 4];
      acc[0][0] = fmaf(a01.x, b4.x, acc[0][0]); acc[0][1] = fmaf(a01.x, b4.y, acc[0][1]);
      acc[0][2] = fmaf(a01.x, b4.z, acc[0][2]); acc[0][3] = fmaf(a01.x, b4.w, acc[0][3]);
      acc[1][0] = fmaf(a01.y, b4.x, acc[1][0]); acc[1][1] = fmaf(a01.y, b4.y, acc[1][1]);
      acc[1][2] = fmaf(a01.y, b4.z, acc[1][2]); acc[1][3] = fmaf(a01.y, b4.w, acc[1][3]);
    }
    __syncthreads();
  }
#pragma unroll
  for (int i = 0; i < 2; ++i) {
    int m = bm + ty * 2 + i;
    if (m > R0) continue;   // M = R0+1
    *(float4*)&C[(size_t)m * N + bn + tx * 4] =
        make_float4(acc[i][0], acc[i][1], acc[i][2], acc[i][3]);
  }
}

// ---------------- K2: Q GEMM tiles FIRST (split-K), then edge pass (no hist) ----------------
__global__ __launch_bounds__(256) void fill_and_Q(const int* __restrict__ srcI,
                                                  const int* __restrict__ dstI,
                                                  int* __restrict__ cursor,
                                                  int* __restrict__ edst,
                                                  const float* __restrict__ Wg2,
                                                  const float* __restrict__ bg2,
                                                  const float* __restrict__ Wc1,
                                                  float* __restrict__ Q, int n_edges) {
  __shared__ float As[16 * 34];
  __shared__ float Bs[16 * 68];
  int b = blockIdx.x;
  int t = threadIdx.x;
  if (b < KSPLIT_TILES) {
    int ks = b & 1;
    int tile = b >> 1;
    gemm_stack_tile(Wg2, bg2, Wc1, nullptr, Q + (size_t)ks * PQ_ELEMS,
                    256, 512, 512, tile, ks * 256, ks * 256 + 256, As, Bs, t);
  } else {
    int eb = b - KSPLIT_TILES;
    int base = eb * (256 * EPT) + t;
    int s[EPT], d[EPT], c[EPT];
    bool v[EPT];
#pragma unroll
    for (int u = 0; u < EPT; ++u) {
      int i = base + u * 256;
      v[u] = i < n_edges;
      s[u] = v[u] ? srcI[i] : 0;
    }
#pragma unroll
    for (int u = 0; u < EPT; ++u) {
      int i = base + u * 256;
      d[u] = v[u] ? dstI[i] : 0;
    }
#pragma unroll
    for (int u = 0; u < EPT; ++u)
      if (v[u]) c[u] = atomicAdd(&cursor[(size_t)s[u] * CSTR], 1);
#pragma unroll
    for (int u = 0; u < EPT; ++u)
      if (v[u]) edst[(size_t)s[u] * CAP + c[u]] = d[u];
  }
}

// ---------------- K2.5: build wT (uint8, exact small ints <= ~41) from adjacency ----------------
// wT[k][g] = (batch[k]==g) + #{d in N(k): batch[d]==g}
__global__ __launch_bounds__(256) void build_wT(const int* __restrict__ batch,
                                                const int* __restrict__ deg,
                                                const int* __restrict__ edst,
                                                unsigned char* __restrict__ wT, int n_nodes) {
  int node = blockIdx.x * 4 + (threadIdx.x >> 6);
  int g = threadIdx.x & 63;
  if (node >= n_nodes) return;
  int end = deg[(size_t)node * CSTR];
  const int* nb = edst + (size_t)node * CAP;
  int acc = (batch[node] == g) ? 1 : 0;
  int i = 0;
  for (; i + 7 < end; i += 8) {
    int d0 = nb[i], d1 = nb[i + 1], d2 = nb[i + 2], d3 = nb[i + 3];
    int d4 = nb[i + 4], d5 = nb[i + 5], d6 = nb[i + 6], d7 = nb[i + 7];
    int b0 = batch[d0], b1 = batch[d1], b2 = batch[d2], b3 = batch[d3];
    int b4 = batch[d4], b5 = batch[d5], b6 = batch[d6], b7 = batch[d7];
    acc += ((b0 == g) + (b1 == g)) + ((b2 == g) + (b3 == g)) +
           ((b4 == g) + (b5 == g)) + ((b6 == g) + (b7 == g));
  }
  for (; i < end; ++i) acc += (batch[nb[i]] == g);
  wT[(size_t)node * 64 + g] = (unsigned char)acc;
}

// ---------------- K3: P GEMM tiles, wT colsum (-> cgpad), cT gather ----------------
// cT[k][g] = wT[k][g] + sum_{d in N(k)} wT[d][g]   (<= 1681, exact in fp16)
// colsum[g] = sum_k wT[k][g] = ng[g] + edge-hist[g]  (== head's cg, exact int atomics)
__global__ __launch_bounds__(256) void cT_and_P(const unsigned char* __restrict__ wT,
                                                const int* __restrict__ deg,
                                                const int* __restrict__ edst,
                                                __half* __restrict__ cT,
                                                const float* __restrict__ Wg1,
                                                const float* __restrict__ bg1,
                                                const float* __restrict__ Q,
                                                float* __restrict__ P,
                                                float* __restrict__ cgpad, int n_nodes) {
  __shared__ float As[16 * 34];
  __shared__ float Bs[16 * 68];
  int b = blockIdx.x;
  int t = threadIdx.x;
  if (b < KSPLIT_TILES) {
    int ks = b & 1;
    int tile = b >> 1;
    gemm_stack_tile(Wg1, bg1, Q, Q + PQ_ELEMS, P + (size_t)ks * PQ_ELEMS,
                    256, 512, 512, tile, ks * 256, ks * 256 + 256, As, Bs, t);
  } else if (b < KSPLIT_TILES + COLSUM_BLOCKS) {
    int cb = b - KSPLIT_TILES;
    int w = t >> 6;
    int g = t & 63;
    int rpb = (n_nodes + COLSUM_BLOCKS - 1) / COLSUM_BLOCKS;
    int r0 = cb * rpb;
    int r1 = r0 + rpb < n_nodes ? r0 + rpb : n_nodes;
    float acc = 0.f;
    for (int r = r0 + w; r < r1; r += 4)
      acc += (float)wT[(size_t)r * 64 + g];
    float* cs = As;   // reuse 4*64 of the 544-float As buffer
    cs[w * 64 + g] = acc;
    __syncthreads();
    if (t < 64) {
      float tot = cs[t] + cs[64 + t] + cs[128 + t] + cs[192 + t];
      if (tot != 0.f) atomicAdd(&cgpad[t * CGS], tot);   // exact: integer-valued
    }
  } else {
    int node = (b - KSPLIT_TILES - COLSUM_BLOCKS) * 4 + (t >> 6);
    int g = t & 63;
    if (node >= n_nodes) return;
    float acc = (float)wT[(size_t)node * 64 + g];
    int end = deg[(size_t)node * CSTR];
    const int* nb = edst + (size_t)node * CAP;
    int i = 0;
    for (; i + 7 < end; i += 8) {
      int d0 = nb[i], d1 = nb[i + 1], d2 = nb[i + 2], d3 = nb[i + 3];
      int d4 = nb[i + 4], d5 = nb[i + 5], d6 = nb[i + 6], d7 = nb[i + 7];
      float v0 = (float)wT[(size_t)d0 * 64 + g];
      float v1 = (float)wT[(size_t)d1 * 64 + g];
      float v2 = (float)wT[(size_t)d2 * 64 + g];
      float v3 = (float)wT[(size_t)d3 * 64 + g];
      float v4 = (float)wT[(size_t)d4 * 64 + g];
      float v5 = (float)wT[(size_t)d5 * 64 + g];
      float v6 = (float)wT[(size_t)d6 * 64 + g];
      float v7 = (float)wT[(size_t)d7 * 64 + g];
      acc += ((v0 + v1) + (v2 + v3)) + ((v4 + v5) + (v6 + v7));
    }
    for (; i + 3 < end; i += 4) {
      int d0 = nb[i], d1 = nb[i + 1], d2 = nb[i + 2], d3 = nb[i + 3];
      acc += (float)wT[(size_t)d0 * 64 + g] + (float)wT[(size_t)d1 * 64 + g] +
             (float)wT[(size_t)d2 * 64 + g] + (float)wT[(size_t)d3 * 64 + g];
    }
    for (; i < end; ++i) acc += (float)wT[(size_t)nb[i] * 64 + g];
    cT[(size_t)node * 64 + g] = __float2half_rn(acc);
  }
}

// ---------------- K4: U-GEMM (fp16 LDS tile, natural VGPR, dbuf x stream) ----------------
#define LOADX(X, KB)                                                      \
  _Pragma("unroll")                                                       \
  for (int t_ = 0; t_ < 4; ++t_) {                                        \
    X[t_] = x2[(size_t)(k0 + (KB) + t_) * 256 + ncol];                    \
  }

#define COMPX(X, KB)                                                      \
  _Pragma("unroll")                                                       \
  for (int t_ = 0; t_ < 4; ++t_) {                                        \
    const __half2* hp_ = (const __half2*)&scT[(KB) + t_][w * 8];          \
    float2 c0_ = __half22float2(hp_[0]);                                  \
    float2 c1_ = __half22float2(hp_[1]);                                  \
    float2 c2_ = __half22float2(hp_[2]);                                  \
    float2 c3_ = __half22float2(hp_[3]);                                  \
    float cv_[8] = {c0_.x, c0_.y, c1_.x, c1_.y, c2_.x, c2_.y, c3_.x, c3_.y}; \
    _Pragma("unroll")                                                     \
    for (int q_ = 0; q_ < 8; ++q_) {                                      \
      acc[q_].x = fmaf(cv_[q_], X[t_].x, acc[q_].x);                      \
      acc[q_].y = fmaf(cv_[q_], X[t_].y, acc[q_].y);                      \
    }                                                                     \
  }

__global__ __launch_bounds__(512) void ugemm(const float* __restrict__ x,
                                             const __half* __restrict__ cT,
                                             float* __restrict__ Upart, int n_nodes) {
  __shared__ __half scT[KCH][64];  // 20 KB fp16
  int c = blockIdx.y;
  int nx = blockIdx.x;            // column quarter
  int t = threadIdx.x;
  int w = t >> 6;                 // wave 0..7
  int g = t & 63;                 // lane
  int k0 = c * KCH;
  int kmax = (n_nodes - k0) < KCH ? (n_nodes - k0) : KCH;  // 160 (125*160==20000)
  {
    // coalesced fp16 copy (4 halves per thread per iter)
    const uint2* src = (const uint2*)(cT + (size_t)k0 * 64);
    uint2* dst = (uint2*)(&scT[0][0]);
    int limit = kmax * 16;        // kmax*64 halves / 4
    for (int i = t; i < limit; i += 512) dst[i] = src[i];
  }
  __syncthreads();
  const float2* x2 = (const float2*)x;
  int ncol = nx * 64 + g;         // one float2 column per lane
  float2 acc[8];
#pragma unroll
  for (int q = 0; q < 8; ++q) acc[q] = make_float2(0.f, 0.f);
  float2 xa[4], xb[4];
  LOADX(xa, 0);
  for (int kk = 0; kk < kmax; kk += 8) {
    LOADX(xb, kk + 4);
    COMPX(xa, kk);
    if (kk + 8 < kmax) { LOADX(xa, kk + 8); }
    COMPX(xb, kk + 4);
  }
  float2* up = (float2*)Upart;
#pragma unroll
  for (int q = 0; q < 8; ++q) {
    int gg = w * 8 + q;
    up[((size_t)c * 64 + gg) * 256 + ncol] = acc[q];
  }
}

// ---------------- Upart reduce: Ured[s][g][n] = sum_{c in split s} Upart[c][g][n] ----------------
__global__ __launch_bounds__(128) void reduce_U(const float* __restrict__ Upart,
                                                float* __restrict__ Ured) {
  int g = blockIdx.x;   // 0..63
  int s = blockIdx.y;   // 0..RSPLIT-1
  int t = threadIdx.x;  // 0..127 float4 over 512
  int c0 = s * CPS;
  int c1 = (c0 + CPS < NCHUNK) ? c0 + CPS : NCHUNK;
  const float4* up = (const float4*)Upart;
  float4 acc = make_float4(0.f, 0.f, 0.f, 0.f);
  for (int c = c0; c < c1; ++c) {
    float4 v = up[((size_t)c * 64 + g) * 128 + t];
    acc.x += v.x; acc.y += v.y; acc.z += v.z; acc.w += v.w;
  }
  ((float4*)Ured)[((size_t)s * 64 + g) * 128 + t] = acc;
}

// ---------------- fused head ----------------
// P = two K-partials of [Wc; v1]; Q = two K-partials of [*; v2]; cg = colsum(wT) (cgpad)
__global__ __launch_bounds__(256) void head(const float* __restrict__ Ured,
                                            const float* __restrict__ P,
                                            const float* __restrict__ Q,
                                            const float* __restrict__ ng,
                                            const float* __restrict__ cgpad,
                                            const float* __restrict__ bc1,
                                            const float* __restrict__ Wc2,
                                            const float* __restrict__ bc2,
                                            float* __restrict__ out) {
  int g = blockIdx.x;
  int j = threadIdx.x;
  const float* Wc0 = P;
  const float* Wc1p = P + (size_t)PQ_ELEMS;
  const float* v1a = P + (size_t)512 * 256;
  const float* v1b = P + (size_t)PQ_ELEMS + (size_t)512 * 256;
  const float* v2a = Q + (size_t)512 * 256;
  const float* v2b = Q + (size_t)PQ_ELEMS + (size_t)512 * 256;
  __shared__ float p[512];
  float s0 = 0.f, s1 = 0.f;
#pragma unroll
  for (int s = 0; s < RSPLIT; ++s) {
    s0 += Ured[((size_t)s * 64 + g) * DIM + j];
    s1 += Ured[((size_t)s * 64 + g) * DIM + 256 + j];
  }
  p[j] = s0;
  p[j + 256] = s1;
  __syncthreads();
  float cg = cgpad[g * CGS];     // == ng + edge-hist (wT column sum)
  float acc = bc1[j] + cg * (v1a[j] + v1b[j]) + ng[g] * (v2a[j] + v2b[j]);
  for (int k = 0; k < 512; ++k) {
    float w = Wc0[k * 256 + j] + Wc1p[k * 256 + j];
    acc = fmaf(p[k], w, acc);
  }
  float z = fmaxf(acc, 0.f);
  float part = z * Wc2[j];
  for (int off = 32; off > 0; off >>= 1) part += __shfl_down(part, off, 64);
  __shared__ float red[4];
  if ((j & 63) == 0) red[j >> 6] = part;
  __syncthreads();
  if (j == 0) {
    float tot = red[0] + red[1] + red[2] + red[3] + bc2[0];
    out[g] = 1.f / (1.f + expf(-tot));
  }
}

extern "C" void kernel_launch(void* const* d_in, const int* in_sizes, int n_in,
                              void* d_out, int out_size, void* d_ws, size_t ws_size,
                              hipStream_t stream) {
  const float* x    = (const float*)d_in[0];
  const int*   ei   = (const int*)d_in[1];
  const int*   batch= (const int*)d_in[2];
  const float* Wg1  = (const float*)d_in[3];
  const float* bg1  = (const float*)d_in[4];
  const float* Wg2  = (const float*)d_in[5];
  const float* bg2  = (const float*)d_in[6];
  const float* Wc1  = (const float*)d_in[7];
  const float* bc1  = (const float*)d_in[8];
  const float* Wc2  = (const float*)d_in[9];
  const float* bc2  = (const float*)d_in[10];
  float* out = (float*)d_out;

  int n_edges = in_sizes[1] / 2;
  int n_nodes = in_sizes[2];
  const int* srcI = ei;
  const int* dstI = ei + n_edges;

  char* ws = (char*)d_ws;
  size_t off = 0;
  auto alloc = [&](size_t bytes) { char* p = ws + off; off += (bytes + 255) & ~(size_t)255; return p; };
  unsigned char* wT = (unsigned char*)alloc((size_t)N_NODES * 64);           // 1.28 MB
  __half* cT   = (__half*)alloc((size_t)N_NODES * 64 * sizeof(__half));      // 2.56 MB
  float* Upart = (float*)alloc((size_t)NCHUNK * 64 * DIM * sizeof(float));   // 16.4 MB
  float* Ured  = (float*)alloc((size_t)RSPLIT * 64 * DIM * sizeof(float));   // 655 KB
  float* Q     = (float*)alloc((size_t)2 * PQ_ELEMS * sizeof(float));        // split-K partials
  float* P     = (float*)alloc((size_t)2 * PQ_ELEMS * sizeof(float));        // split-K partials
  float* ng    = (float*)alloc(NG * sizeof(float));
  float* cgpad = (float*)alloc(NG * CGS * sizeof(float));
  int* cursor  = (int*)alloc((size_t)N_NODES * CSTR * sizeof(int));          // 1.28 MB padded
  int* edst    = (int*)alloc((size_t)N_NODES * CAP * sizeof(int));           // 5.12 MB padded adj

  // K1: cursor zero + ng/cgpad init
  node_init<<<INIT_BLOCKS, 256, 0, stream>>>(batch, cursor, ng, cgpad, n_nodes);
  // K2: Q GEMM tiles (split-K, first) || edge pass (adjacency fill only, no hist)
  fill_and_Q<<<KSPLIT_TILES + EDGE_BLOCKS, 256, 0, stream>>>(srcI, dstI, cursor, edst,
                                                             Wg2, bg2, Wc1, Q, n_edges);
  // K2.5: wT (uint8) from adjacency (pure gather, 5000 blocks)
  build_wT<<<NODE_BLOCKS, 256, 0, stream>>>(batch, cursor, edst, wT, n_nodes);
  // K3: P GEMM tiles (split-K) || wT colsum (cg) || cT gather (uint8 rows, 5000 blocks)
  cT_and_P<<<KSPLIT_TILES + COLSUM_BLOCKS + NODE_BLOCKS, 256, 0, stream>>>(
      wT, cursor, edst, cT, Wg1, bg1, Q, P, cgpad, n_nodes);
  // K4: U partials (fp16 LDS tile, natural VGPR allocation, double-buffered x stream)
  ugemm<<<dim3(NSPLIT, NCHUNK), 512, 0, stream>>>(x, cT, Upart, n_nodes);
  // K5: reduce partials
  reduce_U<<<dim3(64, RSPLIT), 128, 0, stream>>>(Upart, Ured);
  // K6: head
  head<<<NG, 256, 0, stream>>>(Ured, P, Q, ng, cgpad, bc1, Wc2, bc2, out);
}